// Round 22
// baseline (59.099 us; speedup 1.0000x reference)
//
#include <hip/hip_runtime.h>
#include <hip/hip_bf16.h>
#include <math.h>

#define BB 4
#define NTOK 4096
#define CC 256
#define NH 4
#define HD 64
#define CKV 128

typedef _Float16 half8 __attribute__((ext_vector_type(8)));
typedef _Float16 half2v __attribute__((ext_vector_type(2)));
typedef float    f32x4 __attribute__((ext_vector_type(4)));
typedef unsigned int uint2v __attribute__((ext_vector_type(2)));
typedef unsigned int uint4v __attribute__((ext_vector_type(4)));

__device__ __forceinline__ unsigned int pkrtz_u(float a, float b) {
  return __builtin_bit_cast(unsigned int, __builtin_amdgcn_cvt_pkrtz(a, b));
}
__device__ __forceinline__ float exp2_fast(float x) {
  float r;
  asm("v_exp_f32 %0, %1" : "=v"(r) : "v"(x));
  return r;
}
__device__ __forceinline__ int swzi(int row, int d) {
  return row * 64 + (d ^ ((row & 7) << 3));
}
__device__ __forceinline__ int swzv(int row, int d) {
  return row * 64 + (d ^ (((row >> 1) & 7) << 3));
}
__device__ __forceinline__ int swz128(int row, int d) {
  return row * 128 + (d ^ ((row & 7) << 3));
}
__device__ __forceinline__ f32x4 mfma16(half8 a, half8 b, f32x4 c) {
  return __builtin_amdgcn_mfma_f32_16x16x32_f16(a, b, c, 0, 0, 0);
}

// ---------------------------------------------------------------------------
// conv1x1+BN+SiLU v2: no Xs buffer — A-fragments gathered directly from the
// fp16 transpose scratch T (8 scalar LDS reads per fragment). 2 barriers per
// K-chunk (was 3); LDS 25 KB -> 5 blocks/CU. q-conv output pre-scaled.
// ---------------------------------------------------------------------------
__global__ __launch_bounds__(256) void conv_fused(
    const float* __restrict__ x, const float* __restrict__ y,
    const float* __restrict__ qw, const float* __restrict__ qg_, const float* __restrict__ qb,
    const float* __restrict__ qm, const float* __restrict__ qv,
    const float* __restrict__ kw, const float* __restrict__ kg_, const float* __restrict__ kb,
    const float* __restrict__ km, const float* __restrict__ kvv,
    _Float16* __restrict__ qout, _Float16* __restrict__ kvout)
{
  const int ptile = blockIdx.x, oy = blockIdx.y, b = blockIdx.z;
  const bool isq = oy < 4;
  const float* Xsrc = isq ? x : y;
  const float* W    = isq ? qw : kw;
  const float* gam  = isq ? qg_ : kg_;
  const float* bet  = isq ? qb : kb;
  const float* mea  = isq ? qm : km;
  const float* var  = isq ? qv : kvv;
  _Float16*    Yout = isq ? qout : kvout;
  const int otile = isq ? oy : oy - 4;
  const int COUT  = isq ? 256 : 128;
  const float OSCALE = isq ? (0.125f * 1.44269504f) : 1.0f;

  __shared__ _Float16 T[64 * 132];   // [c][p] fp16
  __shared__ _Float16 Ws[64 * 64];

  const int t = threadIdx.x, wave = t >> 6, lane = t & 63;
  const int lm = lane & 15, lg = lane >> 4;
  const float* Xb = Xsrc + (size_t)b * CC * NTOK + ptile * 128;
  const float* Wb = W + otile * 64 * 256;

  f32x4 acc[2][4];
  #pragma unroll
  for (int m = 0; m < 2; ++m)
    #pragma unroll
    for (int n = 0; n < 4; ++n) acc[m][n] = (f32x4){0.f, 0.f, 0.f, 0.f};

  // per-lane row coordinates for direct-from-T A fragments
  const int pm0 = wave * 32 + lm;        // m=0 row
  const int pm1 = wave * 32 + 16 + lm;   // m=1 row

  for (int c0 = 0; c0 < 256; c0 += 64) {
    __syncthreads();   // prev chunk's T/Ws consumers done
    #pragma unroll
    for (int i = 0; i < 8; ++i) {
      int c = (t >> 5) + i * 8;
      int pcol = (t & 31) * 4;
      float4 v = *(const float4*)&Xb[(size_t)(c0 + c) * NTOK + pcol];
      *(uint2v*)&T[c * 132 + pcol] = (uint2v){pkrtz_u(v.x, v.y), pkrtz_u(v.z, v.w)};
    }
    #pragma unroll
    for (int i = 0; i < 2; ++i) {
      int u = t + i * 256; int o = u >> 3, ch = u & 7;
      const float* ws = &Wb[o * 256 + c0 + ch * 8];
      uint4v h;
      #pragma unroll
      for (int j = 0; j < 4; ++j) h[j] = pkrtz_u(ws[j * 2], ws[j * 2 + 1]);
      *(uint4v*)&Ws[swzi(o, ch * 8)] = h;
    }
    __syncthreads();   // T/Ws ready
    #pragma unroll
    for (int kh = 0; kh < 2; ++kh) {
      half8 af[2], bf[4];
      const int cb = kh * 32 + lg * 8;
      #pragma unroll
      for (int j = 0; j < 8; ++j) {
        af[0][j] = T[(cb + j) * 132 + pm0];
        af[1][j] = T[(cb + j) * 132 + pm1];
      }
      #pragma unroll
      for (int n = 0; n < 4; ++n) bf[n] = *(half8*)&Ws[swzi(n * 16 + lm, kh * 32 + lg * 8)];
      #pragma unroll
      for (int m = 0; m < 2; ++m)
        #pragma unroll
        for (int n = 0; n < 4; ++n)
          acc[m][n] = mfma16(af[m], bf[n], acc[m][n]);
    }
  }

  float ga[4], bb[4];
  #pragma unroll
  for (int n = 0; n < 4; ++n) {
    int o = otile * 64 + n * 16 + lm;
    float g = gam[o] * rsqrtf(var[o] + 1e-5f);
    ga[n] = g;
    bb[n] = bet[o] - mea[o] * g;
  }
  _Float16* Yb = Yout + (size_t)b * COUT * NTOK;
  #pragma unroll
  for (int m = 0; m < 2; ++m)
    #pragma unroll
    for (int n = 0; n < 4; ++n) {
      float r[4];
      #pragma unroll
      for (int rr = 0; rr < 4; ++rr) {
        float v = acc[m][n][rr] * ga[n] + bb[n];
        r[rr] = (v / (1.f + __expf(-v))) * OSCALE;
      }
      int o = otile * 64 + n * 16 + lm;
      int p = ptile * 128 + wave * 32 + m * 16 + lg * 4;
      *(uint2v*)&Yb[(size_t)o * NTOK + p] =
          (uint2v){pkrtz_u(r[0], r[1]), pkrtz_u(r[2], r[3])};
    }
}

// ---------------------------------------------------------------------------
// fp16 MFMA flash attention v9 (measured best, unchanged)
// ---------------------------------------------------------------------------
__global__ __launch_bounds__(512) void attn_mfma9(
    const _Float16* __restrict__ Q,
    const _Float16* __restrict__ KV,
    _Float16* __restrict__ O)
{
  const int nt = blockIdx.x, hh = blockIdx.y, b = blockIdx.z;
  const int n0 = nt * 256;
  const int t = threadIdx.x, wave = t >> 6, lane = t & 63;
  const int lm = lane & 15, lg = lane >> 4;
  const int wq = wave * 32;

  __shared__ _Float16 Kl[2][64 * 64];
  __shared__ _Float16 Vt[2][64 * 64];
  __shared__ _Float16 Pl[256 * 64];

  const _Float16* Qb  = Q  + (size_t)b * (CC * NTOK)  + hh * 64;
  const _Float16* KVb = KV + (size_t)b * (CKV * NTOK) + hh * 64;

  half8 qf[2][2];
  #pragma unroll
  for (int qg = 0; qg < 2; ++qg) {
    int n = n0 + wq + qg * 16 + lm;
    const _Float16* src = Qb + (n >> 4) * 4096 + (n & 15) * 256;
    qf[qg][0] = *(const half8*)(src + lg * 8);
    qf[qg][1] = *(const half8*)(src + 32 + lg * 8);
  }

  half8 ones;
  #pragma unroll
  for (int j = 0; j < 8; ++j) ones[j] = (_Float16)1.f;

  f32x4 acc[2][4], accl[2];
  float m_run[2];
  #pragma unroll
  for (int qg = 0; qg < 2; ++qg) {
    m_run[qg] = -1e30f;
    accl[qg] = (f32x4){0.f, 0.f, 0.f, 0.f};
    #pragma unroll
    for (int dg = 0; dg < 4; ++dg) acc[qg][dg] = (f32x4){0.f, 0.f, 0.f, 0.f};
  }

  const int kkey = t >> 3, kch = t & 7;
  const int dvp = (t & 31) * 2, kgv = t >> 5;
  const int koffA = swzi(kkey, kch * 8);
  const int voffA = swzv(dvp, kgv * 4), voffB = swzv(dvp + 1, kgv * 4);
  const _Float16* kp = KVb + (size_t)(kkey >> 3) * 4096 + (kkey & 7) * 512 + kch * 8;
  const _Float16* vp = KVb + (size_t)(kgv >> 1) * 4096 + (kgv & 1) * 2048 + 256 + dvp;

  half8 kreg;
  unsigned int vreg[4];

#define PREFETCH() do {                                   \
    kreg = *(const half8*)kp;                             \
    _Pragma("unroll")                                     \
    for (int j = 0; j < 4; ++j)                           \
      vreg[j] = *(const unsigned int*)(vp + j * 512);     \
    kp += 8 * 4096; vp += 8 * 4096;                       \
  } while (0)

#define STORE_LDS(buf) do {                               \
    *(half8*)&Kl[buf][koffA] = kreg;                      \
    unsigned int l0 = (vreg[0] & 0xffffu) | (vreg[1] << 16);      \
    unsigned int l1 = (vreg[2] & 0xffffu) | (vreg[3] << 16);      \
    unsigned int h0 = (vreg[0] >> 16) | (vreg[1] & 0xffff0000u);  \
    unsigned int h1 = (vreg[2] >> 16) | (vreg[3] & 0xffff0000u);  \
    *(uint2v*)&Vt[buf][voffA] = (uint2v){l0, l1};                 \
    *(uint2v*)&Vt[buf][voffB] = (uint2v){h0, h1};                 \
  } while (0)

#define BODY(curb, tt) do {                                            \
    if ((tt) < 15) PREFETCH();                                         \
    f32x4 sc[2][4];                                                    \
    __builtin_amdgcn_s_setprio(1);                                     \
    _Pragma("unroll")                                                  \
    for (int kt = 0; kt < 4; ++kt) {                                   \
      half8 kf0 = *(half8*)&Kl[curb][swzi(kt * 16 + lm, lg * 8)];      \
      half8 kf1 = *(half8*)&Kl[curb][swzi(kt * 16 + lm, 32 + lg * 8)]; \
      _Pragma("unroll")                                                \
      for (int qg = 0; qg < 2; ++qg) {                                 \
        f32x4 z = (f32x4){0.f, 0.f, 0.f, 0.f};                         \
        z = mfma16(kf0, qf[qg][0], z);                                 \
        z = mfma16(kf1, qf[qg][1], z);                                 \
        sc[qg][kt] = z;                                                \
      }                                                                \
    }                                                                  \
    __builtin_amdgcn_s_setprio(0);                                     \
    _Pragma("unroll")                                                  \
    for (int qg = 0; qg < 2; ++qg) {                                   \
      float t0 = fmaxf(fmaxf(sc[qg][0][0], sc[qg][0][1]), sc[qg][0][2]);   \
      float t1 = fmaxf(fmaxf(sc[qg][0][3], sc[qg][1][0]), sc[qg][1][1]);   \
      float t2 = fmaxf(fmaxf(sc[qg][1][2], sc[qg][1][3]), sc[qg][2][0]);   \
      float t3 = fmaxf(fmaxf(sc[qg][2][1], sc[qg][2][2]), sc[qg][2][3]);   \
      float t4 = fmaxf(fmaxf(sc[qg][3][0], sc[qg][3][1]), sc[qg][3][2]);   \
      float tm = fmaxf(fmaxf(fmaxf(t0, t1), t2),                           \
                       fmaxf(fmaxf(t3, t4), sc[qg][3][3]));                \
      tm = fmaxf(tm, __shfl_xor(tm, 16, 64));                          \
      tm = fmaxf(tm, __shfl_xor(tm, 32, 64));                          \
      if (__any(tm > m_run[qg] + 8.0f)) {                              \
        float mnew = fmaxf(m_run[qg], tm);                             \
        float corr = exp2_fast(m_run[qg] - mnew);                      \
        _Pragma("unroll")                                              \
        for (int dg = 0; dg < 4; ++dg) acc[qg][dg] *= corr;            \
        accl[qg] *= corr;                                              \
        m_run[qg] = mnew;                                              \
      }                                                                \
      int qrow = wq + qg * 16 + lm;                                    \
      _Pragma("unroll")                                                \
      for (int kt = 0; kt < 4; ++kt) {                                 \
        float p0 = exp2_fast(sc[qg][kt][0] - m_run[qg]);               \
        float p1 = exp2_fast(sc[qg][kt][1] - m_run[qg]);               \
        float p2 = exp2_fast(sc[qg][kt][2] - m_run[qg]);               \
        float p3 = exp2_fast(sc[qg][kt][3] - m_run[qg]);               \
        *(uint2v*)&Pl[swzi(qrow, kt * 16 + lg * 4)] =                  \
            (uint2v){pkrtz_u(p0, p1), pkrtz_u(p2, p3)};                \
      }                                                                \
    }                                                                  \
    __builtin_amdgcn_s_setprio(1);                                     \
    _Pragma("unroll")                                                  \
    for (int ka = 0; ka < 2; ++ka) {                                   \
      half8 pf[2];                                                     \
      _Pragma("unroll")                                                \
      for (int qg = 0; qg < 2; ++qg) {                                 \
        pf[qg] = *(half8*)&Pl[swzi(wq + qg * 16 + lm, ka * 32 + lg * 8)];  \
        accl[qg] = mfma16(ones, pf[qg], accl[qg]);                     \
      }                                                                \
      _Pragma("unroll")                                                \
      for (int dg = 0; dg < 4; ++dg) {                                 \
        half8 vf = *(half8*)&Vt[curb][swzv(dg * 16 + lm, ka * 32 + lg * 8)]; \
        _Pragma("unroll")                                              \
        for (int qg = 0; qg < 2; ++qg)                                 \
          acc[qg][dg] = mfma16(vf, pf[qg], acc[qg][dg]);               \
      }                                                                \
    }                                                                  \
    __builtin_amdgcn_s_setprio(0);                                     \
    if ((tt) < 15) STORE_LDS(curb ^ 1);                                \
    __syncthreads();                                                   \
  } while (0)

  PREFETCH();
  STORE_LDS(0);
  __syncthreads();

  #pragma unroll 1
  for (int it8 = 0; it8 < 8; ++it8) {
    BODY(0, 2 * it8);
    BODY(1, 2 * it8 + 1);
  }

  #pragma unroll
  for (int qg = 0; qg < 2; ++qg) {
    float inv = 1.f / accl[qg][0];
    int n = n0 + wq + qg * 16 + lm;
    _Float16* dst = O + ((size_t)(b * NH + hh) * NTOK + n) * 64;
    #pragma unroll
    for (int dg = 0; dg < 4; ++dg) {
      *(uint2v*)(dst + dg * 16 + lg * 4) =
          (uint2v){pkrtz_u(acc[qg][dg][0] * inv, acc[qg][dg][1] * inv),
                   pkrtz_u(acc[qg][dg][2] * inv, acc[qg][dg][3] * inv)};
    }
  }
#undef PREFETCH
#undef STORE_LDS
#undef BODY
}

// ---------------------------------------------------------------------------
// projection: fp16 MFMA, BK=128 (measured best, unchanged)
// ---------------------------------------------------------------------------
__global__ __launch_bounds__(256) void proj_mfma(
    const _Float16* __restrict__ A, const float* __restrict__ Wp,
    const float* __restrict__ bias, float* __restrict__ Out)
{
  const int rtile = blockIdx.x, ctile = blockIdx.y;
  __shared__ _Float16 As[128 * 128];
  __shared__ _Float16 Ws[64 * 128];
  const int t = threadIdx.x, wave = t >> 6, lane = t & 63;
  const int lm = lane & 15, lg = lane >> 4;
  const _Float16* Ab = A + (size_t)rtile * 128 * 256;
  const float* Wb = Wp + ctile * 64 * 256;
  f32x4 acc[2][4];
  #pragma unroll
  for (int m = 0; m < 2; ++m)
    #pragma unroll
    for (int n = 0; n < 4; ++n) acc[m][n] = (f32x4){0.f, 0.f, 0.f, 0.f};

  for (int c0 = 0; c0 < 256; c0 += 128) {
    __syncthreads();
    #pragma unroll
    for (int i = 0; i < 8; ++i) {
      int u = t + i * 256; int r = u >> 4, ch = u & 15;
      *(half8*)&As[swz128(r, ch * 8)] = *(const half8*)&Ab[(size_t)r * 256 + c0 + ch * 8];
    }
    #pragma unroll
    for (int i = 0; i < 4; ++i) {
      int u = t + i * 256; int o = u >> 4, ch = u & 15;
      const float* ws = &Wb[o * 256 + c0 + ch * 8];
      uint4v h;
      #pragma unroll
      for (int j = 0; j < 4; ++j) h[j] = pkrtz_u(ws[j * 2], ws[j * 2 + 1]);
      *(uint4v*)&Ws[swz128(o, ch * 8)] = h;
    }
    __syncthreads();
    #pragma unroll
    for (int kh = 0; kh < 4; ++kh) {
      half8 af[2], bf[4];
      #pragma unroll
      for (int m = 0; m < 2; ++m) af[m] = *(half8*)&As[swz128(wave * 32 + m * 16 + lm, kh * 32 + lg * 8)];
      #pragma unroll
      for (int n = 0; n < 4; ++n) bf[n] = *(half8*)&Ws[swz128(n * 16 + lm, kh * 32 + lg * 8)];
      #pragma unroll
      for (int m = 0; m < 2; ++m)
        #pragma unroll
        for (int n = 0; n < 4; ++n)
          acc[m][n] = mfma16(af[m], bf[n], acc[m][n]);
    }
  }
  float* Ob = Out + (size_t)rtile * 128 * 256 + ctile * 64;
  #pragma unroll
  for (int n = 0; n < 4; ++n) {
    float bia = bias[ctile * 64 + n * 16 + lm];
    #pragma unroll
    for (int m = 0; m < 2; ++m)
      #pragma unroll
      for (int rr = 0; rr < 4; ++rr)
        Ob[(size_t)(wave * 32 + m * 16 + lg * 4 + rr) * 256 + n * 16 + lm] =
            acc[m][n][rr] + bia;
  }
}

// ---------------------------------------------------------------------------
extern "C" void kernel_launch(void* const* d_in, const int* in_sizes, int n_in,
                              void* d_out, int out_size, void* d_ws, size_t ws_size,
                              hipStream_t stream) {
  const float* x        = (const float*)d_in[0];
  const float* y        = (const float*)d_in[1];
  const float* q_w      = (const float*)d_in[4];
  const float* q_gamma  = (const float*)d_in[5];
  const float* q_beta   = (const float*)d_in[6];
  const float* q_mean   = (const float*)d_in[7];
  const float* q_var    = (const float*)d_in[8];
  const float* kv_w     = (const float*)d_in[9];
  const float* kv_gamma = (const float*)d_in[10];
  const float* kv_beta  = (const float*)d_in[11];
  const float* kv_mean  = (const float*)d_in[12];
  const float* kv_var   = (const float*)d_in[13];
  const float* proj_w   = (const float*)d_in[14];
  const float* proj_b   = (const float*)d_in[15];
  float* out = (float*)d_out;

  _Float16* qbn  = (_Float16*)d_ws;                   // B*256*4096 halfs
  _Float16* kvbn = qbn  + (size_t)BB * CC * NTOK;     // B*128*4096
  _Float16* aout = kvbn + (size_t)BB * CKV * NTOK;    // B*4*4096*64

  conv_fused<<<dim3(32, 6, BB), 256, 0, stream>>>(
      x, y, q_w, q_gamma, q_beta, q_mean, q_var,
      kv_w, kv_gamma, kv_beta, kv_mean, kv_var, qbn, kvbn);
  attn_mfma9<<<dim3(16, NH, BB), 512, 0, stream>>>(qbn, kvbn, aout);
  proj_mfma<<<dim3(128, 4), 256, 0, stream>>>(aout, proj_w, proj_b, out);
}

// Round 23
// 55.537 us; speedup vs baseline: 1.0641x; 1.0641x over previous
//
#include <hip/hip_runtime.h>
#include <hip/hip_bf16.h>
#include <math.h>

#define BB 4
#define NTOK 4096
#define CC 256
#define NH 4
#define HD 64
#define CKV 128

typedef _Float16 half8 __attribute__((ext_vector_type(8)));
typedef _Float16 half2v __attribute__((ext_vector_type(2)));
typedef float    f32x4 __attribute__((ext_vector_type(4)));
typedef unsigned int uint2v __attribute__((ext_vector_type(2)));
typedef unsigned int uint4v __attribute__((ext_vector_type(4)));

__device__ __forceinline__ unsigned int pkrtz_u(float a, float b) {
  return __builtin_bit_cast(unsigned int, __builtin_amdgcn_cvt_pkrtz(a, b));
}
__device__ __forceinline__ float exp2_fast(float x) {
  float r;
  asm("v_exp_f32 %0, %1" : "=v"(r) : "v"(x));
  return r;
}
__device__ __forceinline__ int swzi(int row, int d) {
  return row * 64 + (d ^ ((row & 7) << 3));
}
__device__ __forceinline__ int swzv(int row, int d) {
  return row * 64 + (d ^ (((row >> 1) & 7) << 3));
}
__device__ __forceinline__ int swz128(int row, int d) {
  return row * 128 + (d ^ ((row & 7) << 3));
}
__device__ __forceinline__ f32x4 mfma16(half8 a, half8 b, f32x4 c) {
  return __builtin_amdgcn_mfma_f32_16x16x32_f16(a, b, c, 0, 0, 0);
}

// ---------------------------------------------------------------------------
// conv1x1+BN+SiLU, fully fused (round-20/21 measured best).
// X cast fp16 during first staging store; q-conv output pre-scaled.
// ---------------------------------------------------------------------------
__global__ __launch_bounds__(256) void conv_fused(
    const float* __restrict__ x, const float* __restrict__ y,
    const float* __restrict__ qw, const float* __restrict__ qg_, const float* __restrict__ qb,
    const float* __restrict__ qm, const float* __restrict__ qv,
    const float* __restrict__ kw, const float* __restrict__ kg_, const float* __restrict__ kb,
    const float* __restrict__ km, const float* __restrict__ kvv,
    _Float16* __restrict__ qout, _Float16* __restrict__ kvout)
{
  const int ptile = blockIdx.x, oy = blockIdx.y, b = blockIdx.z;
  const bool isq = oy < 4;
  const float* Xsrc = isq ? x : y;
  const float* W    = isq ? qw : kw;
  const float* gam  = isq ? qg_ : kg_;
  const float* bet  = isq ? qb : kb;
  const float* mea  = isq ? qm : km;
  const float* var  = isq ? qv : kvv;
  _Float16*    Yout = isq ? qout : kvout;
  const int otile = isq ? oy : oy - 4;
  const int COUT  = isq ? 256 : 128;
  const float OSCALE = isq ? (0.125f * 1.44269504f) : 1.0f;

  __shared__ _Float16 T[64 * 132];
  __shared__ _Float16 Xs[128 * 64];
  __shared__ _Float16 Ws[64 * 64];

  const int t = threadIdx.x, wave = t >> 6, lane = t & 63;
  const int lm = lane & 15, lg = lane >> 4;
  const float* Xb = Xsrc + (size_t)b * CC * NTOK + ptile * 128;
  const float* Wb = W + otile * 64 * 256;

  f32x4 acc[2][4];
  #pragma unroll
  for (int m = 0; m < 2; ++m)
    #pragma unroll
    for (int n = 0; n < 4; ++n) acc[m][n] = (f32x4){0.f, 0.f, 0.f, 0.f};

  for (int c0 = 0; c0 < 256; c0 += 64) {
    __syncthreads();
    #pragma unroll
    for (int i = 0; i < 8; ++i) {
      int c = (t >> 5) + i * 8;
      int pcol = (t & 31) * 4;
      float4 v = *(const float4*)&Xb[(size_t)(c0 + c) * NTOK + pcol];
      *(uint2v*)&T[c * 132 + pcol] = (uint2v){pkrtz_u(v.x, v.y), pkrtz_u(v.z, v.w)};
    }
    #pragma unroll
    for (int i = 0; i < 2; ++i) {
      int u = t + i * 256; int o = u >> 3, ch = u & 7;
      const float* ws = &Wb[o * 256 + c0 + ch * 8];
      uint4v h;
      #pragma unroll
      for (int j = 0; j < 4; ++j) h[j] = pkrtz_u(ws[j * 2], ws[j * 2 + 1]);
      *(uint4v*)&Ws[swzi(o, ch * 8)] = h;
    }
    __syncthreads();
    {
      int p = t & 127, chh = (t >> 7) * 4;
      #pragma unroll
      for (int cc = 0; cc < 4; ++cc) {
        int ch = chh + cc;
        half8 h;
        #pragma unroll
        for (int j = 0; j < 8; ++j) h[j] = T[(ch * 8 + j) * 132 + p];
        *(half8*)&Xs[swzi(p, ch * 8)] = h;
      }
    }
    __syncthreads();
    #pragma unroll
    for (int kh = 0; kh < 2; ++kh) {
      half8 af[2], bf[4];
      #pragma unroll
      for (int m = 0; m < 2; ++m) af[m] = *(half8*)&Xs[swzi(wave * 32 + m * 16 + lm, kh * 32 + lg * 8)];
      #pragma unroll
      for (int n = 0; n < 4; ++n) bf[n] = *(half8*)&Ws[swzi(n * 16 + lm, kh * 32 + lg * 8)];
      #pragma unroll
      for (int m = 0; m < 2; ++m)
        #pragma unroll
        for (int n = 0; n < 4; ++n)
          acc[m][n] = mfma16(af[m], bf[n], acc[m][n]);
    }
  }

  float ga[4], bb[4];
  #pragma unroll
  for (int n = 0; n < 4; ++n) {
    int o = otile * 64 + n * 16 + lm;
    float g = gam[o] * rsqrtf(var[o] + 1e-5f);
    ga[n] = g;
    bb[n] = bet[o] - mea[o] * g;
  }
  _Float16* Yb = Yout + (size_t)b * COUT * NTOK;
  #pragma unroll
  for (int m = 0; m < 2; ++m)
    #pragma unroll
    for (int n = 0; n < 4; ++n) {
      float r[4];
      #pragma unroll
      for (int rr = 0; rr < 4; ++rr) {
        float v = acc[m][n][rr] * ga[n] + bb[n];
        r[rr] = (v / (1.f + __expf(-v))) * OSCALE;
      }
      int o = otile * 64 + n * 16 + lm;
      int p = ptile * 128 + wave * 32 + m * 16 + lg * 4;
      *(uint2v*)&Yb[(size_t)o * NTOK + p] =
          (uint2v){pkrtz_u(r[0], r[1]), pkrtz_u(r[2], r[3])};
    }
}

// ---------------------------------------------------------------------------
// fp16 MFMA flash attention v9 (measured best, unchanged): 8 waves x 32
// q-rows = 256 q-rows/block, 512 threads, dbuf K/Vt, integer packing,
// v_exp asm, ones-MFMA denominator, setprio. Q pre-scaled by conv.
// ---------------------------------------------------------------------------
__global__ __launch_bounds__(512) void attn_mfma9(
    const _Float16* __restrict__ Q,
    const _Float16* __restrict__ KV,
    _Float16* __restrict__ O)
{
  const int nt = blockIdx.x, hh = blockIdx.y, b = blockIdx.z;
  const int n0 = nt * 256;
  const int t = threadIdx.x, wave = t >> 6, lane = t & 63;
  const int lm = lane & 15, lg = lane >> 4;
  const int wq = wave * 32;

  __shared__ _Float16 Kl[2][64 * 64];
  __shared__ _Float16 Vt[2][64 * 64];
  __shared__ _Float16 Pl[256 * 64];

  const _Float16* Qb  = Q  + (size_t)b * (CC * NTOK)  + hh * 64;
  const _Float16* KVb = KV + (size_t)b * (CKV * NTOK) + hh * 64;

  half8 qf[2][2];
  #pragma unroll
  for (int qg = 0; qg < 2; ++qg) {
    int n = n0 + wq + qg * 16 + lm;
    const _Float16* src = Qb + (n >> 4) * 4096 + (n & 15) * 256;
    qf[qg][0] = *(const half8*)(src + lg * 8);
    qf[qg][1] = *(const half8*)(src + 32 + lg * 8);
  }

  half8 ones;
  #pragma unroll
  for (int j = 0; j < 8; ++j) ones[j] = (_Float16)1.f;

  f32x4 acc[2][4], accl[2];
  float m_run[2];
  #pragma unroll
  for (int qg = 0; qg < 2; ++qg) {
    m_run[qg] = -1e30f;
    accl[qg] = (f32x4){0.f, 0.f, 0.f, 0.f};
    #pragma unroll
    for (int dg = 0; dg < 4; ++dg) acc[qg][dg] = (f32x4){0.f, 0.f, 0.f, 0.f};
  }

  const int kkey = t >> 3, kch = t & 7;
  const int dvp = (t & 31) * 2, kgv = t >> 5;
  const int koffA = swzi(kkey, kch * 8);
  const int voffA = swzv(dvp, kgv * 4), voffB = swzv(dvp + 1, kgv * 4);
  const _Float16* kp = KVb + (size_t)(kkey >> 3) * 4096 + (kkey & 7) * 512 + kch * 8;
  const _Float16* vp = KVb + (size_t)(kgv >> 1) * 4096 + (kgv & 1) * 2048 + 256 + dvp;

  half8 kreg;
  unsigned int vreg[4];

#define PREFETCH() do {                                   \
    kreg = *(const half8*)kp;                             \
    _Pragma("unroll")                                     \
    for (int j = 0; j < 4; ++j)                           \
      vreg[j] = *(const unsigned int*)(vp + j * 512);     \
    kp += 8 * 4096; vp += 8 * 4096;                       \
  } while (0)

#define STORE_LDS(buf) do {                               \
    *(half8*)&Kl[buf][koffA] = kreg;                      \
    unsigned int l0 = (vreg[0] & 0xffffu) | (vreg[1] << 16);      \
    unsigned int l1 = (vreg[2] & 0xffffu) | (vreg[3] << 16);      \
    unsigned int h0 = (vreg[0] >> 16) | (vreg[1] & 0xffff0000u);  \
    unsigned int h1 = (vreg[2] >> 16) | (vreg[3] & 0xffff0000u);  \
    *(uint2v*)&Vt[buf][voffA] = (uint2v){l0, l1};                 \
    *(uint2v*)&Vt[buf][voffB] = (uint2v){h0, h1};                 \
  } while (0)

#define BODY(curb, tt) do {                                            \
    if ((tt) < 15) PREFETCH();                                         \
    f32x4 sc[2][4];                                                    \
    __builtin_amdgcn_s_setprio(1);                                     \
    _Pragma("unroll")                                                  \
    for (int kt = 0; kt < 4; ++kt) {                                   \
      half8 kf0 = *(half8*)&Kl[curb][swzi(kt * 16 + lm, lg * 8)];      \
      half8 kf1 = *(half8*)&Kl[curb][swzi(kt * 16 + lm, 32 + lg * 8)]; \
      _Pragma("unroll")                                                \
      for (int qg = 0; qg < 2; ++qg) {                                 \
        f32x4 z = (f32x4){0.f, 0.f, 0.f, 0.f};                         \
        z = mfma16(kf0, qf[qg][0], z);                                 \
        z = mfma16(kf1, qf[qg][1], z);                                 \
        sc[qg][kt] = z;                                                \
      }                                                                \
    }                                                                  \
    __builtin_amdgcn_s_setprio(0);                                     \
    _Pragma("unroll")                                                  \
    for (int qg = 0; qg < 2; ++qg) {                                   \
      float t0 = fmaxf(fmaxf(sc[qg][0][0], sc[qg][0][1]), sc[qg][0][2]);   \
      float t1 = fmaxf(fmaxf(sc[qg][0][3], sc[qg][1][0]), sc[qg][1][1]);   \
      float t2 = fmaxf(fmaxf(sc[qg][1][2], sc[qg][1][3]), sc[qg][2][0]);   \
      float t3 = fmaxf(fmaxf(sc[qg][2][1], sc[qg][2][2]), sc[qg][2][3]);   \
      float t4 = fmaxf(fmaxf(sc[qg][3][0], sc[qg][3][1]), sc[qg][3][2]);   \
      float tm = fmaxf(fmaxf(fmaxf(t0, t1), t2),                           \
                       fmaxf(fmaxf(t3, t4), sc[qg][3][3]));                \
      tm = fmaxf(tm, __shfl_xor(tm, 16, 64));                          \
      tm = fmaxf(tm, __shfl_xor(tm, 32, 64));                          \
      if (__any(tm > m_run[qg] + 8.0f)) {                              \
        float mnew = fmaxf(m_run[qg], tm);                             \
        float corr = exp2_fast(m_run[qg] - mnew);                      \
        _Pragma("unroll")                                              \
        for (int dg = 0; dg < 4; ++dg) acc[qg][dg] *= corr;            \
        accl[qg] *= corr;                                              \
        m_run[qg] = mnew;                                              \
      }                                                                \
      int qrow = wq + qg * 16 + lm;                                    \
      _Pragma("unroll")                                                \
      for (int kt = 0; kt < 4; ++kt) {                                 \
        float p0 = exp2_fast(sc[qg][kt][0] - m_run[qg]);               \
        float p1 = exp2_fast(sc[qg][kt][1] - m_run[qg]);               \
        float p2 = exp2_fast(sc[qg][kt][2] - m_run[qg]);               \
        float p3 = exp2_fast(sc[qg][kt][3] - m_run[qg]);               \
        *(uint2v*)&Pl[swzi(qrow, kt * 16 + lg * 4)] =                  \
            (uint2v){pkrtz_u(p0, p1), pkrtz_u(p2, p3)};                \
      }                                                                \
    }                                                                  \
    __builtin_amdgcn_s_setprio(1);                                     \
    _Pragma("unroll")                                                  \
    for (int ka = 0; ka < 2; ++ka) {                                   \
      half8 pf[2];                                                     \
      _Pragma("unroll")                                                \
      for (int qg = 0; qg < 2; ++qg) {                                 \
        pf[qg] = *(half8*)&Pl[swzi(wq + qg * 16 + lm, ka * 32 + lg * 8)];  \
        accl[qg] = mfma16(ones, pf[qg], accl[qg]);                     \
      }                                                                \
      _Pragma("unroll")                                                \
      for (int dg = 0; dg < 4; ++dg) {                                 \
        half8 vf = *(half8*)&Vt[curb][swzv(dg * 16 + lm, ka * 32 + lg * 8)]; \
        _Pragma("unroll")                                              \
        for (int qg = 0; qg < 2; ++qg)                                 \
          acc[qg][dg] = mfma16(vf, pf[qg], acc[qg][dg]);               \
      }                                                                \
    }                                                                  \
    __builtin_amdgcn_s_setprio(0);                                     \
    if ((tt) < 15) STORE_LDS(curb ^ 1);                                \
    __syncthreads();                                                   \
  } while (0)

  PREFETCH();
  STORE_LDS(0);
  __syncthreads();

  #pragma unroll 1
  for (int it8 = 0; it8 < 8; ++it8) {
    BODY(0, 2 * it8);
    BODY(1, 2 * it8 + 1);
  }

  #pragma unroll
  for (int qg = 0; qg < 2; ++qg) {
    float inv = 1.f / accl[qg][0];
    int n = n0 + wq + qg * 16 + lm;
    _Float16* dst = O + ((size_t)(b * NH + hh) * NTOK + n) * 64;
    #pragma unroll
    for (int dg = 0; dg < 4; ++dg) {
      *(uint2v*)(dst + dg * 16 + lg * 4) =
          (uint2v){pkrtz_u(acc[qg][dg][0] * inv, acc[qg][dg][1] * inv),
                   pkrtz_u(acc[qg][dg][2] * inv, acc[qg][dg][3] * inv)};
    }
  }
#undef PREFETCH
#undef STORE_LDS
#undef BODY
}

// ---------------------------------------------------------------------------
// projection: fp16 MFMA, BK=128 (measured best, unchanged)
// ---------------------------------------------------------------------------
__global__ __launch_bounds__(256) void proj_mfma(
    const _Float16* __restrict__ A, const float* __restrict__ Wp,
    const float* __restrict__ bias, float* __restrict__ Out)
{
  const int rtile = blockIdx.x, ctile = blockIdx.y;
  __shared__ _Float16 As[128 * 128];
  __shared__ _Float16 Ws[64 * 128];
  const int t = threadIdx.x, wave = t >> 6, lane = t & 63;
  const int lm = lane & 15, lg = lane >> 4;
  const _Float16* Ab = A + (size_t)rtile * 128 * 256;
  const float* Wb = Wp + ctile * 64 * 256;
  f32x4 acc[2][4];
  #pragma unroll
  for (int m = 0; m < 2; ++m)
    #pragma unroll
    for (int n = 0; n < 4; ++n) acc[m][n] = (f32x4){0.f, 0.f, 0.f, 0.f};

  for (int c0 = 0; c0 < 256; c0 += 128) {
    __syncthreads();
    #pragma unroll
    for (int i = 0; i < 8; ++i) {
      int u = t + i * 256; int r = u >> 4, ch = u & 15;
      *(half8*)&As[swz128(r, ch * 8)] = *(const half8*)&Ab[(size_t)r * 256 + c0 + ch * 8];
    }
    #pragma unroll
    for (int i = 0; i < 4; ++i) {
      int u = t + i * 256; int o = u >> 4, ch = u & 15;
      const float* ws = &Wb[o * 256 + c0 + ch * 8];
      uint4v h;
      #pragma unroll
      for (int j = 0; j < 4; ++j) h[j] = pkrtz_u(ws[j * 2], ws[j * 2 + 1]);
      *(uint4v*)&Ws[swz128(o, ch * 8)] = h;
    }
    __syncthreads();
    #pragma unroll
    for (int kh = 0; kh < 4; ++kh) {
      half8 af[2], bf[4];
      #pragma unroll
      for (int m = 0; m < 2; ++m) af[m] = *(half8*)&As[swz128(wave * 32 + m * 16 + lm, kh * 32 + lg * 8)];
      #pragma unroll
      for (int n = 0; n < 4; ++n) bf[n] = *(half8*)&Ws[swz128(n * 16 + lm, kh * 32 + lg * 8)];
      #pragma unroll
      for (int m = 0; m < 2; ++m)
        #pragma unroll
        for (int n = 0; n < 4; ++n)
          acc[m][n] = mfma16(af[m], bf[n], acc[m][n]);
    }
  }
  float* Ob = Out + (size_t)rtile * 128 * 256 + ctile * 64;
  #pragma unroll
  for (int n = 0; n < 4; ++n) {
    float bia = bias[ctile * 64 + n * 16 + lm];
    #pragma unroll
    for (int m = 0; m < 2; ++m)
      #pragma unroll
      for (int rr = 0; rr < 4; ++rr)
        Ob[(size_t)(wave * 32 + m * 16 + lg * 4 + rr) * 256 + n * 16 + lm] =
            acc[m][n][rr] + bia;
  }
}

// ---------------------------------------------------------------------------
extern "C" void kernel_launch(void* const* d_in, const int* in_sizes, int n_in,
                              void* d_out, int out_size, void* d_ws, size_t ws_size,
                              hipStream_t stream) {
  const float* x        = (const float*)d_in[0];
  const float* y        = (const float*)d_in[1];
  const float* q_w      = (const float*)d_in[4];
  const float* q_gamma  = (const float*)d_in[5];
  const float* q_beta   = (const float*)d_in[6];
  const float* q_mean   = (const float*)d_in[7];
  const float* q_var    = (const float*)d_in[8];
  const float* kv_w     = (const float*)d_in[9];
  const float* kv_gamma = (const float*)d_in[10];
  const float* kv_beta  = (const float*)d_in[11];
  const float* kv_mean  = (const float*)d_in[12];
  const float* kv_var   = (const float*)d_in[13];
  const float* proj_w   = (const float*)d_in[14];
  const float* proj_b   = (const float*)d_in[15];
  float* out = (float*)d_out;

  _Float16* qbn  = (_Float16*)d_ws;                   // B*256*4096 halfs
  _Float16* kvbn = qbn  + (size_t)BB * CC * NTOK;     // B*128*4096
  _Float16* aout = kvbn + (size_t)BB * CKV * NTOK;    // B*4*4096*64

  conv_fused<<<dim3(32, 6, BB), 256, 0, stream>>>(
      x, y, q_w, q_gamma, q_beta, q_mean, q_var,
      kv_w, kv_gamma, kv_beta, kv_mean, kv_var, qbn, kvbn);
  attn_mfma9<<<dim3(16, NH, BB), 512, 0, stream>>>(qbn, kvbn, aout);
  proj_mfma<<<dim3(128, 4), 256, 0, stream>>>(aout, proj_w, proj_b, out);
}

// Round 24
// 54.899 us; speedup vs baseline: 1.0765x; 1.0116x over previous
//
#include <hip/hip_runtime.h>
#include <hip/hip_bf16.h>
#include <math.h>

#define BB 4
#define NTOK 4096
#define CC 256
#define NH 4
#define HD 64
#define CKV 128

typedef _Float16 half8 __attribute__((ext_vector_type(8)));
typedef _Float16 half2v __attribute__((ext_vector_type(2)));
typedef float    f32x4 __attribute__((ext_vector_type(4)));
typedef unsigned int uint2v __attribute__((ext_vector_type(2)));
typedef unsigned int uint4v __attribute__((ext_vector_type(4)));

__device__ __forceinline__ unsigned int pkrtz_u(float a, float b) {
  return __builtin_bit_cast(unsigned int, __builtin_amdgcn_cvt_pkrtz(a, b));
}
__device__ __forceinline__ float exp2_fast(float x) {
  float r;
  asm("v_exp_f32 %0, %1" : "=v"(r) : "v"(x));
  return r;
}
__device__ __forceinline__ int swzi(int row, int d) {
  return row * 64 + (d ^ ((row & 7) << 3));
}
__device__ __forceinline__ int swzv(int row, int d) {
  return row * 64 + (d ^ (((row >> 1) & 7) << 3));
}
__device__ __forceinline__ int swz128(int row, int d) {
  return row * 128 + (d ^ ((row & 7) << 3));
}
__device__ __forceinline__ f32x4 mfma16(half8 a, half8 b, f32x4 c) {
  return __builtin_amdgcn_mfma_f32_16x16x32_f16(a, b, c, 0, 0, 0);
}

// ---------------------------------------------------------------------------
// conv1x1+BN+SiLU, fully fused (measured best).
// X cast fp16 during first staging store; q-conv output pre-scaled by
// 0.125*log2(e) so attention scores emerge in log2 domain.
// ---------------------------------------------------------------------------
__global__ __launch_bounds__(256) void conv_fused(
    const float* __restrict__ x, const float* __restrict__ y,
    const float* __restrict__ qw, const float* __restrict__ qg_, const float* __restrict__ qb,
    const float* __restrict__ qm, const float* __restrict__ qv,
    const float* __restrict__ kw, const float* __restrict__ kg_, const float* __restrict__ kb,
    const float* __restrict__ km, const float* __restrict__ kvv,
    _Float16* __restrict__ qout, _Float16* __restrict__ kvout)
{
  const int ptile = blockIdx.x, oy = blockIdx.y, b = blockIdx.z;
  const bool isq = oy < 4;
  const float* Xsrc = isq ? x : y;
  const float* W    = isq ? qw : kw;
  const float* gam  = isq ? qg_ : kg_;
  const float* bet  = isq ? qb : kb;
  const float* mea  = isq ? qm : km;
  const float* var  = isq ? qv : kvv;
  _Float16*    Yout = isq ? qout : kvout;
  const int otile = isq ? oy : oy - 4;
  const int COUT  = isq ? 256 : 128;
  const float OSCALE = isq ? (0.125f * 1.44269504f) : 1.0f;

  __shared__ _Float16 T[64 * 132];
  __shared__ _Float16 Xs[128 * 64];
  __shared__ _Float16 Ws[64 * 64];

  const int t = threadIdx.x, wave = t >> 6, lane = t & 63;
  const int lm = lane & 15, lg = lane >> 4;
  const float* Xb = Xsrc + (size_t)b * CC * NTOK + ptile * 128;
  const float* Wb = W + otile * 64 * 256;

  f32x4 acc[2][4];
  #pragma unroll
  for (int m = 0; m < 2; ++m)
    #pragma unroll
    for (int n = 0; n < 4; ++n) acc[m][n] = (f32x4){0.f, 0.f, 0.f, 0.f};

  for (int c0 = 0; c0 < 256; c0 += 64) {
    __syncthreads();
    #pragma unroll
    for (int i = 0; i < 8; ++i) {
      int c = (t >> 5) + i * 8;
      int pcol = (t & 31) * 4;
      float4 v = *(const float4*)&Xb[(size_t)(c0 + c) * NTOK + pcol];
      *(uint2v*)&T[c * 132 + pcol] = (uint2v){pkrtz_u(v.x, v.y), pkrtz_u(v.z, v.w)};
    }
    #pragma unroll
    for (int i = 0; i < 2; ++i) {
      int u = t + i * 256; int o = u >> 3, ch = u & 7;
      const float* ws = &Wb[o * 256 + c0 + ch * 8];
      uint4v h;
      #pragma unroll
      for (int j = 0; j < 4; ++j) h[j] = pkrtz_u(ws[j * 2], ws[j * 2 + 1]);
      *(uint4v*)&Ws[swzi(o, ch * 8)] = h;
    }
    __syncthreads();
    {
      int p = t & 127, chh = (t >> 7) * 4;
      #pragma unroll
      for (int cc = 0; cc < 4; ++cc) {
        int ch = chh + cc;
        half8 h;
        #pragma unroll
        for (int j = 0; j < 8; ++j) h[j] = T[(ch * 8 + j) * 132 + p];
        *(half8*)&Xs[swzi(p, ch * 8)] = h;
      }
    }
    __syncthreads();
    #pragma unroll
    for (int kh = 0; kh < 2; ++kh) {
      half8 af[2], bf[4];
      #pragma unroll
      for (int m = 0; m < 2; ++m) af[m] = *(half8*)&Xs[swzi(wave * 32 + m * 16 + lm, kh * 32 + lg * 8)];
      #pragma unroll
      for (int n = 0; n < 4; ++n) bf[n] = *(half8*)&Ws[swzi(n * 16 + lm, kh * 32 + lg * 8)];
      #pragma unroll
      for (int m = 0; m < 2; ++m)
        #pragma unroll
        for (int n = 0; n < 4; ++n)
          acc[m][n] = mfma16(af[m], bf[n], acc[m][n]);
    }
  }

  float ga[4], bb[4];
  #pragma unroll
  for (int n = 0; n < 4; ++n) {
    int o = otile * 64 + n * 16 + lm;
    float g = gam[o] * rsqrtf(var[o] + 1e-5f);
    ga[n] = g;
    bb[n] = bet[o] - mea[o] * g;
  }
  _Float16* Yb = Yout + (size_t)b * COUT * NTOK;
  #pragma unroll
  for (int m = 0; m < 2; ++m)
    #pragma unroll
    for (int n = 0; n < 4; ++n) {
      float r[4];
      #pragma unroll
      for (int rr = 0; rr < 4; ++rr) {
        float v = acc[m][n][rr] * ga[n] + bb[n];
        r[rr] = (v / (1.f + __expf(-v))) * OSCALE;
      }
      int o = otile * 64 + n * 16 + lm;
      int p = ptile * 128 + wave * 32 + m * 16 + lg * 4;
      *(uint2v*)&Yb[(size_t)o * NTOK + p] =
          (uint2v){pkrtz_u(r[0], r[1]), pkrtz_u(r[2], r[3])};
    }
}

// ---------------------------------------------------------------------------
// fp16 MFMA flash attention v9 (measured best): 8 waves x 32 q-rows =
// 256 q-rows/block, 512 threads, dbuf K/Vt, integer packing, v_exp asm,
// ones-MFMA denominator, setprio. Q pre-scaled by conv.
// ---------------------------------------------------------------------------
__global__ __launch_bounds__(512) void attn_mfma9(
    const _Float16* __restrict__ Q,
    const _Float16* __restrict__ KV,
    _Float16* __restrict__ O)
{
  const int nt = blockIdx.x, hh = blockIdx.y, b = blockIdx.z;
  const int n0 = nt * 256;
  const int t = threadIdx.x, wave = t >> 6, lane = t & 63;
  const int lm = lane & 15, lg = lane >> 4;
  const int wq = wave * 32;

  __shared__ _Float16 Kl[2][64 * 64];
  __shared__ _Float16 Vt[2][64 * 64];
  __shared__ _Float16 Pl[256 * 64];

  const _Float16* Qb  = Q  + (size_t)b * (CC * NTOK)  + hh * 64;
  const _Float16* KVb = KV + (size_t)b * (CKV * NTOK) + hh * 64;

  half8 qf[2][2];
  #pragma unroll
  for (int qg = 0; qg < 2; ++qg) {
    int n = n0 + wq + qg * 16 + lm;
    const _Float16* src = Qb + (n >> 4) * 4096 + (n & 15) * 256;
    qf[qg][0] = *(const half8*)(src + lg * 8);
    qf[qg][1] = *(const half8*)(src + 32 + lg * 8);
  }

  half8 ones;
  #pragma unroll
  for (int j = 0; j < 8; ++j) ones[j] = (_Float16)1.f;

  f32x4 acc[2][4], accl[2];
  float m_run[2];
  #pragma unroll
  for (int qg = 0; qg < 2; ++qg) {
    m_run[qg] = -1e30f;
    accl[qg] = (f32x4){0.f, 0.f, 0.f, 0.f};
    #pragma unroll
    for (int dg = 0; dg < 4; ++dg) acc[qg][dg] = (f32x4){0.f, 0.f, 0.f, 0.f};
  }

  const int kkey = t >> 3, kch = t & 7;
  const int dvp = (t & 31) * 2, kgv = t >> 5;
  const int koffA = swzi(kkey, kch * 8);
  const int voffA = swzv(dvp, kgv * 4), voffB = swzv(dvp + 1, kgv * 4);
  const _Float16* kp = KVb + (size_t)(kkey >> 3) * 4096 + (kkey & 7) * 512 + kch * 8;
  const _Float16* vp = KVb + (size_t)(kgv >> 1) * 4096 + (kgv & 1) * 2048 + 256 + dvp;

  half8 kreg;
  unsigned int vreg[4];

#define PREFETCH() do {                                   \
    kreg = *(const half8*)kp;                             \
    _Pragma("unroll")                                     \
    for (int j = 0; j < 4; ++j)                           \
      vreg[j] = *(const unsigned int*)(vp + j * 512);     \
    kp += 8 * 4096; vp += 8 * 4096;                       \
  } while (0)

#define STORE_LDS(buf) do {                               \
    *(half8*)&Kl[buf][koffA] = kreg;                      \
    unsigned int l0 = (vreg[0] & 0xffffu) | (vreg[1] << 16);      \
    unsigned int l1 = (vreg[2] & 0xffffu) | (vreg[3] << 16);      \
    unsigned int h0 = (vreg[0] >> 16) | (vreg[1] & 0xffff0000u);  \
    unsigned int h1 = (vreg[2] >> 16) | (vreg[3] & 0xffff0000u);  \
    *(uint2v*)&Vt[buf][voffA] = (uint2v){l0, l1};                 \
    *(uint2v*)&Vt[buf][voffB] = (uint2v){h0, h1};                 \
  } while (0)

#define BODY(curb, tt) do {                                            \
    if ((tt) < 15) PREFETCH();                                         \
    f32x4 sc[2][4];                                                    \
    __builtin_amdgcn_s_setprio(1);                                     \
    _Pragma("unroll")                                                  \
    for (int kt = 0; kt < 4; ++kt) {                                   \
      half8 kf0 = *(half8*)&Kl[curb][swzi(kt * 16 + lm, lg * 8)];      \
      half8 kf1 = *(half8*)&Kl[curb][swzi(kt * 16 + lm, 32 + lg * 8)]; \
      _Pragma("unroll")                                                \
      for (int qg = 0; qg < 2; ++qg) {                                 \
        f32x4 z = (f32x4){0.f, 0.f, 0.f, 0.f};                         \
        z = mfma16(kf0, qf[qg][0], z);                                 \
        z = mfma16(kf1, qf[qg][1], z);                                 \
        sc[qg][kt] = z;                                                \
      }                                                                \
    }                                                                  \
    __builtin_amdgcn_s_setprio(0);                                     \
    _Pragma("unroll")                                                  \
    for (int qg = 0; qg < 2; ++qg) {                                   \
      float t0 = fmaxf(fmaxf(sc[qg][0][0], sc[qg][0][1]), sc[qg][0][2]);   \
      float t1 = fmaxf(fmaxf(sc[qg][0][3], sc[qg][1][0]), sc[qg][1][1]);   \
      float t2 = fmaxf(fmaxf(sc[qg][1][2], sc[qg][1][3]), sc[qg][2][0]);   \
      float t3 = fmaxf(fmaxf(sc[qg][2][1], sc[qg][2][2]), sc[qg][2][3]);   \
      float t4 = fmaxf(fmaxf(sc[qg][3][0], sc[qg][3][1]), sc[qg][3][2]);   \
      float tm = fmaxf(fmaxf(fmaxf(t0, t1), t2),                           \
                       fmaxf(fmaxf(t3, t4), sc[qg][3][3]));                \
      tm = fmaxf(tm, __shfl_xor(tm, 16, 64));                          \
      tm = fmaxf(tm, __shfl_xor(tm, 32, 64));                          \
      if (__any(tm > m_run[qg] + 8.0f)) {                              \
        float mnew = fmaxf(m_run[qg], tm);                             \
        float corr = exp2_fast(m_run[qg] - mnew);                      \
        _Pragma("unroll")                                              \
        for (int dg = 0; dg < 4; ++dg) acc[qg][dg] *= corr;            \
        accl[qg] *= corr;                                              \
        m_run[qg] = mnew;                                              \
      }                                                                \
      int qrow = wq + qg * 16 + lm;                                    \
      _Pragma("unroll")                                                \
      for (int kt = 0; kt < 4; ++kt) {                                 \
        float p0 = exp2_fast(sc[qg][kt][0] - m_run[qg]);               \
        float p1 = exp2_fast(sc[qg][kt][1] - m_run[qg]);               \
        float p2 = exp2_fast(sc[qg][kt][2] - m_run[qg]);               \
        float p3 = exp2_fast(sc[qg][kt][3] - m_run[qg]);               \
        *(uint2v*)&Pl[swzi(qrow, kt * 16 + lg * 4)] =                  \
            (uint2v){pkrtz_u(p0, p1), pkrtz_u(p2, p3)};                \
      }                                                                \
    }                                                                  \
    __builtin_amdgcn_s_setprio(1);                                     \
    _Pragma("unroll")                                                  \
    for (int ka = 0; ka < 2; ++ka) {                                   \
      half8 pf[2];                                                     \
      _Pragma("unroll")                                                \
      for (int qg = 0; qg < 2; ++qg) {                                 \
        pf[qg] = *(half8*)&Pl[swzi(wq + qg * 16 + lm, ka * 32 + lg * 8)];  \
        accl[qg] = mfma16(ones, pf[qg], accl[qg]);                     \
      }                                                                \
      _Pragma("unroll")                                                \
      for (int dg = 0; dg < 4; ++dg) {                                 \
        half8 vf = *(half8*)&Vt[curb][swzv(dg * 16 + lm, ka * 32 + lg * 8)]; \
        _Pragma("unroll")                                              \
        for (int qg = 0; qg < 2; ++qg)                                 \
          acc[qg][dg] = mfma16(vf, pf[qg], acc[qg][dg]);               \
      }                                                                \
    }                                                                  \
    __builtin_amdgcn_s_setprio(0);                                     \
    if ((tt) < 15) STORE_LDS(curb ^ 1);                                \
    __syncthreads();                                                   \
  } while (0)

  PREFETCH();
  STORE_LDS(0);
  __syncthreads();

  #pragma unroll 1
  for (int it8 = 0; it8 < 8; ++it8) {
    BODY(0, 2 * it8);
    BODY(1, 2 * it8 + 1);
  }

  #pragma unroll
  for (int qg = 0; qg < 2; ++qg) {
    float inv = 1.f / accl[qg][0];
    int n = n0 + wq + qg * 16 + lm;
    _Float16* dst = O + ((size_t)(b * NH + hh) * NTOK + n) * 64;
    #pragma unroll
    for (int dg = 0; dg < 4; ++dg) {
      *(uint2v*)(dst + dg * 16 + lg * 4) =
          (uint2v){pkrtz_u(acc[qg][dg][0] * inv, acc[qg][dg][1] * inv),
                   pkrtz_u(acc[qg][dg][2] * inv, acc[qg][dg][3] * inv)};
    }
  }
#undef PREFETCH
#undef STORE_LDS
#undef BODY
}

// ---------------------------------------------------------------------------
// projection: fp16 MFMA, BK=128 (measured best)
// ---------------------------------------------------------------------------
__global__ __launch_bounds__(256) void proj_mfma(
    const _Float16* __restrict__ A, const float* __restrict__ Wp,
    const float* __restrict__ bias, float* __restrict__ Out)
{
  const int rtile = blockIdx.x, ctile = blockIdx.y;
  __shared__ _Float16 As[128 * 128];
  __shared__ _Float16 Ws[64 * 128];
  const int t = threadIdx.x, wave = t >> 6, lane = t & 63;
  const int lm = lane & 15, lg = lane >> 4;
  const _Float16* Ab = A + (size_t)rtile * 128 * 256;
  const float* Wb = Wp + ctile * 64 * 256;
  f32x4 acc[2][4];
  #pragma unroll
  for (int m = 0; m < 2; ++m)
    #pragma unroll
    for (int n = 0; n < 4; ++n) acc[m][n] = (f32x4){0.f, 0.f, 0.f, 0.f};

  for (int c0 = 0; c0 < 256; c0 += 128) {
    __syncthreads();
    #pragma unroll
    for (int i = 0; i < 8; ++i) {
      int u = t + i * 256; int r = u >> 4, ch = u & 15;
      *(half8*)&As[swz128(r, ch * 8)] = *(const half8*)&Ab[(size_t)r * 256 + c0 + ch * 8];
    }
    #pragma unroll
    for (int i = 0; i < 4; ++i) {
      int u = t + i * 256; int o = u >> 4, ch = u & 15;
      const float* ws = &Wb[o * 256 + c0 + ch * 8];
      uint4v h;
      #pragma unroll
      for (int j = 0; j < 4; ++j) h[j] = pkrtz_u(ws[j * 2], ws[j * 2 + 1]);
      *(uint4v*)&Ws[swz128(o, ch * 8)] = h;
    }
    __syncthreads();
    #pragma unroll
    for (int kh = 0; kh < 4; ++kh) {
      half8 af[2], bf[4];
      #pragma unroll
      for (int m = 0; m < 2; ++m) af[m] = *(half8*)&As[swz128(wave * 32 + m * 16 + lm, kh * 32 + lg * 8)];
      #pragma unroll
      for (int n = 0; n < 4; ++n) bf[n] = *(half8*)&Ws[swz128(n * 16 + lm, kh * 32 + lg * 8)];
      #pragma unroll
      for (int m = 0; m < 2; ++m)
        #pragma unroll
        for (int n = 0; n < 4; ++n)
          acc[m][n] = mfma16(af[m], bf[n], acc[m][n]);
    }
  }
  float* Ob = Out + (size_t)rtile * 128 * 256 + ctile * 64;
  #pragma unroll
  for (int n = 0; n < 4; ++n) {
    float bia = bias[ctile * 64 + n * 16 + lm];
    #pragma unroll
    for (int m = 0; m < 2; ++m)
      #pragma unroll
      for (int rr = 0; rr < 4; ++rr)
        Ob[(size_t)(wave * 32 + m * 16 + lg * 4 + rr) * 256 + n * 16 + lm] =
            acc[m][n][rr] + bia;
  }
}

// ---------------------------------------------------------------------------
extern "C" void kernel_launch(void* const* d_in, const int* in_sizes, int n_in,
                              void* d_out, int out_size, void* d_ws, size_t ws_size,
                              hipStream_t stream) {
  const float* x        = (const float*)d_in[0];
  const float* y        = (const float*)d_in[1];
  const float* q_w      = (const float*)d_in[4];
  const float* q_gamma  = (const float*)d_in[5];
  const float* q_beta   = (const float*)d_in[6];
  const float* q_mean   = (const float*)d_in[7];
  const float* q_var    = (const float*)d_in[8];
  const float* kv_w     = (const float*)d_in[9];
  const float* kv_gamma = (const float*)d_in[10];
  const float* kv_beta  = (const float*)d_in[11];
  const float* kv_mean  = (const float*)d_in[12];
  const float* kv_var   = (const float*)d_in[13];
  const float* proj_w   = (const float*)d_in[14];
  const float* proj_b   = (const float*)d_in[15];
  float* out = (float*)d_out;

  _Float16* qbn  = (_Float16*)d_ws;                   // B*256*4096 halfs
  _Float16* kvbn = qbn  + (size_t)BB * CC * NTOK;     // B*128*4096
  _Float16* aout = kvbn + (size_t)BB * CKV * NTOK;    // B*4*4096*64

  conv_fused<<<dim3(32, 6, BB), 256, 0, stream>>>(
      x, y, q_w, q_gamma, q_beta, q_mean, q_var,
      kv_w, kv_gamma, kv_beta, kv_mean, kv_var, qbn, kvbn);
  attn_mfma9<<<dim3(16, NH, BB), 512, 0, stream>>>(qbn, kvbn, aout);
  proj_mfma<<<dim3(128, 4), 256, 0, stream>>>(aout, proj_w, proj_b, out);
}